// Round 4
// baseline (186.586 us; speedup 1.0000x reference)
//
#include <hip/hip_runtime.h>
#include <math.h>

#define NFFT    4096
#define THREADS 512
#define ROWS    4096
#define NX      1024
#define OUTN    2048
#define OFFSET  255
#define PADN    (NFFT + NFFT / 32)

__device__ __forceinline__ int pad(int e) { return e + (e >> 5); }

__device__ __forceinline__ float2 cmulf(float2 a, float2 b) {
  return make_float2(a.x * b.x - a.y * b.y, a.x * b.y + a.y * b.x);
}

// Generic radix-4 Stockham stages [S_BEGIN, S_END), ping-ponging s->d.
// Stage st: l = 1024>>(2*st), m = 1<<(2*st); reads s[i + c*1024] (l*m==1024),
// twiddle w1 = tw[j*step]^(dir), writes d[4*j*m + k + c*m].
// Returns the buffer holding the result (source after final swap).
template <int DIR, int S_BEGIN, int S_END>
__device__ __forceinline__ float2* run_stages(float2* s, float2* d,
                                              const float2* __restrict__ tw,
                                              int tid) {
  int l = 1024 >> (2 * S_BEGIN);
  int m = 1 << (2 * S_BEGIN);
#pragma unroll
  for (int stage = S_BEGIN; stage < S_END; ++stage) {
    const int step = 1024 / l;
#pragma unroll
    for (int t = 0; t < (NFFT / 4) / THREADS; ++t) {
      const int i = tid + t * THREADS;   // butterfly id, 0..1023
      const int k = i & (m - 1);
      const int j = i / m;
      float2 a = s[pad(i)];
      float2 b = s[pad(i + 1024)];
      float2 c = s[pad(i + 2048)];
      float2 e = s[pad(i + 3072)];
      const int ti = j * step;           // < 1024
      float2 w1 = tw[ti];
      float2 w2 = tw[2 * ti];            // < 2048
      if (DIR < 0) { w1.y = -w1.y; w2.y = -w2.y; }
      const float2 w3 = cmulf(w1, w2);
      const float2 apc = make_float2(a.x + c.x, a.y + c.y);
      const float2 amc = make_float2(a.x - c.x, a.y - c.y);
      const float2 bpd = make_float2(b.x + e.x, b.y + e.y);
      const float2 bmd = make_float2(b.x - e.x, b.y - e.y);
      const float2 jb = (DIR > 0) ? make_float2(bmd.y, -bmd.x)
                                  : make_float2(-bmd.y, bmd.x);
      const float2 y0 = make_float2(apc.x + bpd.x, apc.y + bpd.y);
      const float2 y1 = cmulf(w1, make_float2(amc.x + jb.x, amc.y + jb.y));
      const float2 y2 = cmulf(w2, make_float2(apc.x - bpd.x, apc.y - bpd.y));
      const float2 y3 = cmulf(w3, make_float2(amc.x - jb.x, amc.y - jb.y));
      const int o = 4 * j * m + k;
      d[pad(o)]         = y0;
      d[pad(o + m)]     = y1;
      d[pad(o + 2 * m)] = y2;
      d[pad(o + 3 * m)] = y3;
    }
    __syncthreads();
    float2* tmp = s; s = d; d = tmp;
    l >>= 2;
    m <<= 2;
  }
  return s;
}

// Init: G[f] = W0(f)^2 * WL(f) via direct DFT of the short kernels,
// tw[n] = exp(-2*pi*i*n/4096), n < 2048. Recomputed every launch (ws poisoned).
__global__ __launch_bounds__(256) void init_tables(
    const float* __restrict__ w0r, const float* __restrict__ w0i,
    const float* __restrict__ wlr, const float* __restrict__ wli,
    float2* __restrict__ G, float2* __restrict__ tw) {
  const int f = blockIdx.x * blockDim.x + threadIdx.x;
  if (f >= NFFT) return;
  const float cconst = -2.0f * 3.14159265358979323846f / (float)NFFT;
  float w0re = 0.f, w0im = 0.f;
  for (int n = 0; n < 129; ++n) {
    const int mfn = (f * n) & (NFFT - 1);
    float sv, cv;
    __sincosf(cconst * (float)mfn, &sv, &cv);
    const float ar = w0r[n], ai = w0i[n];
    w0re += ar * cv - ai * sv;
    w0im += ar * sv + ai * cv;
  }
  float wlre = 0.f, wlim = 0.f;
  for (int n = 0; n < 257; ++n) {
    const int mfn = (f * n) & (NFFT - 1);
    float sv, cv;
    __sincosf(cconst * (float)mfn, &sv, &cv);
    const float ar = wlr[n], ai = wli[n];
    wlre += ar * cv - ai * sv;
    wlim += ar * sv + ai * cv;
  }
  const float2 W0 = make_float2(w0re, w0im);
  const float2 WL = make_float2(wlre, wlim);
  G[f] = cmulf(cmulf(W0, W0), WL);
  if (f < NFFT / 2) {
    float sv, cv;
    __sincosf(cconst * (float)f, &sv, &cv);
    tw[f] = make_float2(cv, sv);
  }
}

// One block per row. Fwd stage0 fused w/ global load (inputs b=c=e=0 since
// NX == NFFT/4); pointwise X^2*G fused into inv stage0 reads; magnitude +
// crop + store fused into inv stage5 (identity twiddles there).
// __launch_bounds__(512,4): 4 waves/EU min -> VGPR<=128 -> guarantees the
// 2 blocks/CU (16 waves/CU) design point; LDS 2x33.8KB caps at 2 anyway.
__global__ __launch_bounds__(THREADS, 4) void conv_fft(
    const float* __restrict__ xr, const float* __restrict__ xi,
    const float2* __restrict__ G, const float2* __restrict__ tw,
    float* __restrict__ out) {
  __shared__ float2 A[PADN];
  __shared__ float2 B[PADN];
  const int row = blockIdx.x;
  const int tid = threadIdx.x;
  const float* xrow_r = xr + (size_t)row * NX;
  const float* xrow_i = xi + (size_t)row * NX;

  // ---- forward stage 0 (fused load): y_c = w_c * a, writes A ----
#pragma unroll
  for (int t = 0; t < (NFFT / 4) / THREADS; ++t) {
    const int i = tid + t * THREADS;            // 0..1023
    const float2 a = make_float2(xrow_r[i], xrow_i[i]);
    const float2 w1 = tw[i];
    const float2 w2 = tw[2 * i];
    const float2 w3 = cmulf(w1, w2);
    A[pad(4 * i)]     = a;
    A[pad(4 * i + 1)] = cmulf(w1, a);
    A[pad(4 * i + 2)] = cmulf(w2, a);
    A[pad(4 * i + 3)] = cmulf(w3, a);
  }
  __syncthreads();

  // ---- forward stages 1..5: A->B->A->B->A->B, result in B ----
  float2* F = run_stages<1, 1, 6>(A, B, tw, tid);   // == B

  // ---- inverse stage 0 fused with pointwise Z = X^2 * G: read F(B) -> A ----
  {
    float2* s = F;
    float2* d = (F == A) ? B : A;                   // == A
#pragma unroll
    for (int t = 0; t < (NFFT / 4) / THREADS; ++t) {
      const int i = tid + t * THREADS;              // j = i (m=1), k = 0
      float2 a = s[pad(i)];
      float2 b = s[pad(i + 1024)];
      float2 c = s[pad(i + 2048)];
      float2 e = s[pad(i + 3072)];
      a = cmulf(cmulf(a, a), G[i]);
      b = cmulf(cmulf(b, b), G[i + 1024]);
      c = cmulf(cmulf(c, c), G[i + 2048]);
      e = cmulf(cmulf(e, e), G[i + 3072]);
      float2 w1 = tw[i];  w1.y = -w1.y;             // conj for inverse
      float2 w2 = tw[2 * i]; w2.y = -w2.y;
      const float2 w3 = cmulf(w1, w2);
      const float2 apc = make_float2(a.x + c.x, a.y + c.y);
      const float2 amc = make_float2(a.x - c.x, a.y - c.y);
      const float2 bpd = make_float2(b.x + e.x, b.y + e.y);
      const float2 bmd = make_float2(b.x - e.x, b.y - e.y);
      const float2 jb  = make_float2(-bmd.y, bmd.x);  // +i*bmd (inverse)
      const float2 y0 = make_float2(apc.x + bpd.x, apc.y + bpd.y);
      const float2 y1 = cmulf(w1, make_float2(amc.x + jb.x, amc.y + jb.y));
      const float2 y2 = cmulf(w2, make_float2(apc.x - bpd.x, apc.y - bpd.y));
      const float2 y3 = cmulf(w3, make_float2(amc.x - jb.x, amc.y - jb.y));
      const int o = 4 * i;
      d[pad(o)]     = y0;
      d[pad(o + 1)] = y1;
      d[pad(o + 2)] = y2;
      d[pad(o + 3)] = y3;
    }
    __syncthreads();
  }

  // ---- inverse stages 1..4: A->B->A->B->A, result in A ----
  float2* R = run_stages<-1, 1, 5>(A, B, tw, tid);  // == A

  // ---- inverse stage 5 (identity twiddles) fused with |.|, crop, store ----
  const float scale = 1.0f / (float)NFFT;
  float* orow = out + (size_t)row * OUTN;
#pragma unroll
  for (int t = 0; t < (NFFT / 4) / THREADS; ++t) {
    const int i = tid + t * THREADS;                // 0..1023
    const float2 a = R[pad(i)];
    const float2 b = R[pad(i + 1024)];
    const float2 c = R[pad(i + 2048)];
    const float2 e = R[pad(i + 3072)];
    const float2 apc = make_float2(a.x + c.x, a.y + c.y);
    const float2 amc = make_float2(a.x - c.x, a.y - c.y);
    const float2 bpd = make_float2(b.x + e.x, b.y + e.y);
    const float2 bmd = make_float2(b.x - e.x, b.y - e.y);
    const float2 jb  = make_float2(-bmd.y, bmd.x);  // +i*bmd
    // element i -> out[i-255] (i>=255); i+1024 -> out[i+769] (always);
    // i+2048 -> out[i+1793] (i<255); i+3072 out of crop range.
    const float2 y1 = make_float2(amc.x + jb.x, amc.y + jb.y);
    orow[i + 769] = sqrtf(y1.x * y1.x + y1.y * y1.y) * scale;
    if (i >= OFFSET) {
      const float2 y0 = make_float2(apc.x + bpd.x, apc.y + bpd.y);
      orow[i - OFFSET] = sqrtf(y0.x * y0.x + y0.y * y0.y) * scale;
    } else {
      const float2 y2 = make_float2(apc.x - bpd.x, apc.y - bpd.y);
      orow[i + 1793] = sqrtf(y2.x * y2.x + y2.y * y2.y) * scale;
    }
  }
}

extern "C" void kernel_launch(void* const* d_in, const int* in_sizes, int n_in,
                              void* d_out, int out_size, void* d_ws, size_t ws_size,
                              hipStream_t stream) {
  const float* xr  = (const float*)d_in[0];
  const float* xi  = (const float*)d_in[1];
  const float* w0r = (const float*)d_in[2];
  const float* w0i = (const float*)d_in[3];
  const float* wlr = (const float*)d_in[4];
  const float* wli = (const float*)d_in[5];
  float* out = (float*)d_out;
  float2* G  = (float2*)d_ws;                                   // 4096 float2
  float2* tw = (float2*)((char*)d_ws + NFFT * sizeof(float2));  // 2048 float2
  hipLaunchKernelGGL(init_tables, dim3(16), dim3(256), 0, stream,
                     w0r, w0i, wlr, wli, G, tw);
  hipLaunchKernelGGL(conv_fft, dim3(ROWS), dim3(THREADS), 0, stream,
                     xr, xi, G, tw, out);
}

// Round 6
// 144.574 us; speedup vs baseline: 1.2906x; 1.2906x over previous
//
#include <hip/hip_runtime.h>
#include <math.h>

#define NFFT 4096
#define T    256
#define ROWS 4096
#define NX   1024
#define OUTN 2048
#define OFF  255

__device__ __forceinline__ float2 cmulf(float2 a, float2 b) {
  return make_float2(a.x * b.x - a.y * b.y, a.x * b.y + a.y * b.x);
}
__device__ __forceinline__ float2 caddf(float2 a, float2 b) {
  return make_float2(a.x + b.x, a.y + b.y);
}
__device__ __forceinline__ float2 csubf(float2 a, float2 b) {
  return make_float2(a.x - b.x, a.y - b.y);
}
// multiply by -i (fwd) / +i (inv)
template <int DIR> __device__ __forceinline__ float2 mulmi(float2 a) {
  return (DIR > 0) ? make_float2(a.y, -a.x) : make_float2(-a.y, a.x);
}
// multiply by constant twiddle given in FORWARD convention; conj for inverse
template <int DIR> __device__ __forceinline__ float2 cmulc(float2 a, float wr, float wi) {
  const float y = (DIR > 0) ? wi : -wi;
  return make_float2(a.x * wr - a.y * y, a.x * y + a.y * wr);
}

#define C16 0.9238795325112867f
#define S16 0.3826834323650898f
#define RH  0.7071067811865476f

// 16-pt DFT, natural order in/out: o[c] = sum_m v[m] W16^{mc} (DIR=+1) / conj (DIR=-1).
// Decomposed m = r + 4s, c = c4 + 4*chi; fully unrolled, constant indices only.
template <int DIR>
__device__ __forceinline__ void dft16(const float2* v, float2* o) {
  float2 f[16];
#pragma unroll
  for (int r = 0; r < 4; ++r) {
    const float2 a = v[r], b = v[r + 4], c = v[r + 8], d = v[r + 12];
    const float2 apc = caddf(a, c), amc = csubf(a, c);
    const float2 bpd = caddf(b, d), bmd = csubf(b, d);
    const float2 jb = mulmi<DIR>(bmd);
    f[r]      = caddf(apc, bpd);
    f[r + 4]  = caddf(amc, jb);
    f[r + 8]  = csubf(apc, bpd);
    f[r + 12] = csubf(amc, jb);
  }
  // internal twiddles W16^{r*c4} on f[r + 4*c4]
  f[5]  = cmulc<DIR>(f[5],  C16, -S16);   // ^1
  f[6]  = cmulc<DIR>(f[6],  RH,  -RH);    // ^2
  f[7]  = cmulc<DIR>(f[7],  S16, -C16);   // ^3
  f[9]  = cmulc<DIR>(f[9],  RH,  -RH);    // ^2
  f[10] = mulmi<DIR>(f[10]);              // ^4
  f[11] = cmulc<DIR>(f[11], -RH, -RH);    // ^6
  f[13] = cmulc<DIR>(f[13], S16, -C16);   // ^3
  f[14] = cmulc<DIR>(f[14], -RH, -RH);    // ^6
  f[15] = cmulc<DIR>(f[15], -C16, S16);   // ^9
#pragma unroll
  for (int c4 = 0; c4 < 4; ++c4) {
    const float2 a = f[4 * c4], b = f[4 * c4 + 1], c = f[4 * c4 + 2], d = f[4 * c4 + 3];
    const float2 apc = caddf(a, c), amc = csubf(a, c);
    const float2 bpd = caddf(b, d), bmd = csubf(b, d);
    const float2 jb = mulmi<DIR>(bmd);
    o[c4]      = caddf(apc, bpd);
    o[c4 + 4]  = caddf(amc, jb);
    o[c4 + 8]  = csubf(apc, bpd);
    o[c4 + 12] = csubf(amc, jb);
  }
}

// 16-pt DFT where only v[0..3] are nonzero (zero-padded input): inner radix-4
// collapses to broadcast, f[r+4c4] = W16^{r c4} * v[r].
template <int DIR>
__device__ __forceinline__ void dft16_sp4(const float2* v, float2* o) {
#pragma unroll
  for (int c4 = 0; c4 < 4; ++c4) {
    const float2 a = v[0];
    const float2 b = (c4 == 0) ? v[1]
                   : (c4 == 1) ? cmulc<DIR>(v[1], C16, -S16)
                   : (c4 == 2) ? cmulc<DIR>(v[1], RH, -RH)
                               : cmulc<DIR>(v[1], S16, -C16);
    const float2 c = (c4 == 0) ? v[2]
                   : (c4 == 1) ? cmulc<DIR>(v[2], RH, -RH)
                   : (c4 == 2) ? mulmi<DIR>(v[2])
                               : cmulc<DIR>(v[2], -RH, -RH);
    const float2 d = (c4 == 0) ? v[3]
                   : (c4 == 1) ? cmulc<DIR>(v[3], S16, -C16)
                   : (c4 == 2) ? cmulc<DIR>(v[3], -RH, -RH)
                               : cmulc<DIR>(v[3], -C16, S16);
    const float2 apc = caddf(a, c), amc = csubf(a, c);
    const float2 bpd = caddf(b, d), bmd = csubf(b, d);
    const float2 jb = mulmi<DIR>(bmd);
    o[c4]      = caddf(apc, bpd);
    o[c4 + 4]  = caddf(amc, jb);
    o[c4 + 8]  = csubf(apc, bpd);
    o[c4 + 12] = csubf(amc, jb);
  }
}

// u[c] *= step^c (u[0] untouched). step pre-conjugated by caller for inverse.
__device__ __forceinline__ void chain_apply(float2* u, float2 step) {
  float2 w = step;
  u[1] = cmulf(u[1], w);
#pragma unroll
  for (int c = 2; c < 16; ++c) { w = cmulf(w, step); u[c] = cmulf(u[c], w); }
}
// u[c] *= base * step^c.
__device__ __forceinline__ void chain_apply_base(float2* u, float2 base, float2 step) {
  float2 w = base;
  u[0] = cmulf(u[0], w);
#pragma unroll
  for (int c = 1; c < 16; ++c) { w = cmulf(w, step); u[c] = cmulf(u[c], w); }
}

// Init: G[f] = W0(f)^2 * WL(f) / 4096 (IFFT scale folded in);
// tw[n] = exp(-2*pi*i*n/4096) for n < 4096. Recomputed every launch.
__global__ __launch_bounds__(256) void init_tables(
    const float* __restrict__ w0r, const float* __restrict__ w0i,
    const float* __restrict__ wlr, const float* __restrict__ wli,
    float2* __restrict__ G, float2* __restrict__ tw) {
  const int f = blockIdx.x * blockDim.x + threadIdx.x;
  if (f >= NFFT) return;
  const float cconst = -2.0f * 3.14159265358979323846f / (float)NFFT;
  float w0re = 0.f, w0im = 0.f;
  for (int n = 0; n < 129; ++n) {
    const int mfn = (f * n) & (NFFT - 1);
    float sv, cv;
    __sincosf(cconst * (float)mfn, &sv, &cv);
    const float ar = w0r[n], ai = w0i[n];
    w0re += ar * cv - ai * sv;
    w0im += ar * sv + ai * cv;
  }
  float wlre = 0.f, wlim = 0.f;
  for (int n = 0; n < 257; ++n) {
    const int mfn = (f * n) & (NFFT - 1);
    float sv, cv;
    __sincosf(cconst * (float)mfn, &sv, &cv);
    const float ar = wlr[n], ai = wli[n];
    wlre += ar * cv - ai * sv;
    wlim += ar * sv + ai * cv;
  }
  const float2 W0 = make_float2(w0re, w0im);
  const float2 WL = make_float2(wlre, wlim);
  const float2 g = cmulf(cmulf(W0, W0), WL);
  G[f] = make_float2(g.x * (1.0f / NFFT), g.y * (1.0f / NFFT));
  float sv, cv;
  __sincosf(cconst * (float)f, &sv, &cv);
  tw[f] = make_float2(cv, sv);
}

// Register-resident 16^3 FFT. 256 threads, 16 float2/thread, one 32.9KB LDS
// buffer (4 blocks/CU), 2 transposes per FFT, 7 barriers total.
// Decomposition: n = n1 + 16*m1 + 256*m2, k = k2 + 256*k1, k2 = j2 + 16*j1:
//   X = sum_{n1} W16^{n1 k1} W4096^{n1 k2} sum_{m1} W16^{m1 j1} W256^{m1 j2}
//       sum_{m2} W16^{m2 j2} x[n]
// LDS patterns all sit at the b64 4-slot/bank floor (257 stride on ex2).
__global__ __launch_bounds__(T, 4) void conv_fft(
    const float* __restrict__ xr, const float* __restrict__ xi,
    const float2* __restrict__ G, const float2* __restrict__ tw,
    float* __restrict__ out) {
  __shared__ float2 L[16 * 257];
  const int row = blockIdx.x;
  const int t = threadIdx.x;
  const int n1 = t & 15;
  const int hi = t >> 4;          // m1 in stage 1, j2 in stage 2
  const float* __restrict__ rr = xr + (size_t)row * NX;
  const float* __restrict__ ri = xi + (size_t)row * NX;

  float2 e[16], u[16];
  // ---- load: thread t holds x[t + 256*m2]; only m2 < 4 nonzero (NX=1024) ----
#pragma unroll
  for (int m = 0; m < 4; ++m) e[m] = make_float2(rr[t + 256 * m], ri[t + 256 * m]);

  // ================= FORWARD =================
  // stage 1: DFT16 over m2 (sparse: 12/16 inputs zero), twiddle W256^{m1 c}
  dft16_sp4<1>(e, u);
  { float2 s1 = tw[16 * hi]; chain_apply(u, s1); }
#pragma unroll
  for (int c = 0; c < 16; ++c) L[c * 256 + t] = u[c];   // write ex1
  __syncthreads();
#pragma unroll
  for (int m1 = 0; m1 < 16; ++m1) e[m1] = L[hi * 256 + m1 * 16 + n1];  // read ex1
  __syncthreads();
  // stage 2: DFT16 over m1, twiddle W4096^{n1 (j2+16 j1)} = base*step^j1
  dft16<1>(e, u);
  { float2 b2 = tw[n1 * hi]; float2 s2 = tw[16 * n1]; chain_apply_base(u, b2, s2); }
#pragma unroll
  for (int j1 = 0; j1 < 16; ++j1) L[n1 * 257 + hi + 16 * j1] = u[j1];  // write ex2
  __syncthreads();
#pragma unroll
  for (int q = 0; q < 16; ++q) e[q] = L[q * 257 + t];   // read ex2
  // stage 3: DFT16 over n1 -> thread t holds X[t + 256*k1] in u[k1]
  dft16<1>(e, u);

  // ---- pointwise Z = X^2 * G' (G' includes 1/4096) ----
#pragma unroll
  for (int k = 0; k < 16; ++k) {
    const float2 X = u[k];
    e[k] = cmulf(cmulf(X, X), G[t + 256 * k]);
  }
  __syncthreads();   // all ex2 reads done before inverse reuses L

  // ================= INVERSE (conjugated twiddles) =================
  dft16<-1>(e, u);
  { float2 s1 = tw[16 * hi]; s1.y = -s1.y; chain_apply(u, s1); }
#pragma unroll
  for (int c = 0; c < 16; ++c) L[c * 256 + t] = u[c];
  __syncthreads();
#pragma unroll
  for (int m1 = 0; m1 < 16; ++m1) e[m1] = L[hi * 256 + m1 * 16 + n1];
  __syncthreads();
  dft16<-1>(e, u);
  { float2 b2 = tw[n1 * hi]; b2.y = -b2.y;
    float2 s2 = tw[16 * n1]; s2.y = -s2.y; chain_apply_base(u, b2, s2); }
#pragma unroll
  for (int j1 = 0; j1 < 16; ++j1) L[n1 * 257 + hi + 16 * j1] = u[j1];
  __syncthreads();
#pragma unroll
  for (int q = 0; q < 16; ++q) e[q] = L[q * 257 + t];
  dft16<-1>(e, u);   // u[k1] = y[t + 256*k1] (already scaled by 1/4096 via G')

  // ---- magnitude + crop [255, 2303) -> out[0, 2048) ----
  float* __restrict__ orow = out + (size_t)row * OUTN;
#pragma unroll
  for (int k = 1; k < 8; ++k) {
    const float2 y = u[k];
    orow[t + 256 * k - OFF] = sqrtf(y.x * y.x + y.y * y.y);
  }
  if (t == 255) { const float2 y = u[0]; orow[0] = sqrtf(y.x * y.x + y.y * y.y); }
  if (t < 255)  { const float2 y = u[8]; orow[1793 + t] = sqrtf(y.x * y.x + y.y * y.y); }
}

extern "C" void kernel_launch(void* const* d_in, const int* in_sizes, int n_in,
                              void* d_out, int out_size, void* d_ws, size_t ws_size,
                              hipStream_t stream) {
  const float* xr  = (const float*)d_in[0];
  const float* xi  = (const float*)d_in[1];
  const float* w0r = (const float*)d_in[2];
  const float* w0i = (const float*)d_in[3];
  const float* wlr = (const float*)d_in[4];
  const float* wli = (const float*)d_in[5];
  float* out = (float*)d_out;
  float2* G  = (float2*)d_ws;                                   // 4096 float2
  float2* tw = (float2*)((char*)d_ws + NFFT * sizeof(float2));  // 4096 float2
  hipLaunchKernelGGL(init_tables, dim3(16), dim3(256), 0, stream,
                     w0r, w0i, wlr, wli, G, tw);
  hipLaunchKernelGGL(conv_fft, dim3(ROWS), dim3(T), 0, stream,
                     xr, xi, G, tw, out);
}